// Round 5
// baseline (102.260 us; speedup 1.0000x reference)
//
#include <hip/hip_runtime.h>
#include <cstdint>

// BasisFunction1D: out[o,b] = sum_i (1-d)*P[idx,o,i] + d*P[idx+1,o,i]
//   idx,d from Laplace-CDF bucketization of x[i,b] on a 128-chunk grid.
//
// R4 = R3 with compile fix (nontemporal builtins need clang ext_vector types,
// not HIP_vector_type float4).
//
// R3 strategy (R2 geometry + i-sliced XCD-pinned L2 residency):
//   K1 build_q: Q[i][g][o] = pack_f16x2( P[g,o,i], P[g+1,o,i]-P[g,o,i] )  (8.4 MB)
//   K2 build_t: T[i][b]    = pack{ u16 idx | f16 d << 16 }  (elementwise, x layout)
//   K3 main:    i split into 4 slices of 32. Block's XCD = blockIdx&7 (round-
//               robin dispatch); slice = XCD&3 -> per-XCD Q working set 2.1 MB
//               (+T slice ~1 MB) = L2-resident. Inner loop identical to R2:
//               wave owns 2 b's, one global_load_dwordx4 = 2 contiguous 512-B
//               runs; T via s_load_dwordx2. Partials NT-stored (L2 write-around
//               keeps pinned Q hot).
//   K4 reduce:  out = sum of 4 partial slices (21 MB traffic).

#define NG 128   // grids
#define NI 128   // input dim
#define NO 128   // output dim
#define NB 8192  // batch
#define NSL 4    // i-slices
#define ISL 32   // i per slice

using half2v  = __attribute__((ext_vector_type(2))) _Float16;
using float4v = __attribute__((ext_vector_type(4))) float;

__device__ inline uint32_t pack_f16x2(float lo, float hi) {
    _Float16 hl = (_Float16)lo, hh = (_Float16)hi;
    return (uint32_t)__builtin_bit_cast(unsigned short, hl) |
           ((uint32_t)__builtin_bit_cast(unsigned short, hh) << 16);
}

// ---- K1: transpose+delta-pack func_parameter -> Q[i][g][o] (f16x2) ----
__global__ __launch_bounds__(256) void build_q(const float* __restrict__ P,
                                               uint32_t* __restrict__ Q) {
    __shared__ float lp[32][129];
    __shared__ float ln[32][129];
    const int g  = blockIdx.x >> 2;
    const int o0 = (blockIdx.x & 3) * 32;
    const int t  = threadIdx.x;
    #pragma unroll
    for (int p = 0; p < 16; ++p) {
        int e = p * 256 + t;
        int ol = e >> 7, i = e & 127;
        lp[ol][i] = P[(size_t)(g * NO + o0 + ol) * NI + i];
        ln[ol][i] = P[(size_t)((g + 1) * NO + o0 + ol) * NI + i];
    }
    __syncthreads();
    #pragma unroll
    for (int p = 0; p < 16; ++p) {
        int e = p * 256 + t;
        int i = e >> 5, ol = e & 31;
        float pl = lp[ol][i];
        float dd = ln[ol][i] - pl;
        Q[((size_t)i * NG + g) * NO + o0 + ol] = pack_f16x2(pl, dd);
    }
}

// ---- K2: bucketize x -> T[i][b] = {u16 idx | f16 d << 16}; same layout as x ----
__global__ __launch_bounds__(256) void build_t(const float* __restrict__ x,
                                               const float* __restrict__ borders,
                                               const float* __restrict__ icl,
                                               uint32_t* __restrict__ T) {
    const int e0 = (blockIdx.x * 256 + threadIdx.x) * 4;
    const float4 xv = *(const float4*)(x + e0);
    uint32_t r[4];
    const float xs[4] = {xv.x, xv.y, xv.z, xv.w};
    #pragma unroll
    for (int k = 0; k < 4; ++k) {
        float v = xs[k];
        float ea = __expf(-fabsf(v));
        float cdf = v > 0.f ? 1.f - 0.5f * ea : 0.5f * ea;
        int idx = (int)(cdf * 128.f);
        idx = idx > 127 ? 127 : idx;
        float d = (v - borders[idx]) * icl[idx];
        _Float16 hd = (_Float16)d;
        r[k] = (uint32_t)idx |
               ((uint32_t)__builtin_bit_cast(unsigned short, hd) << 16);
    }
    *(uint4*)(T + e0) = make_uint4(r[0], r[1], r[2], r[3]);
}

// ---- K3: main gather-dot. 512 thr, 8 waves, 2 b/wave, i-slice by XCD ----
__global__ __launch_bounds__(512) void main_k(const uint32_t* __restrict__ Q,
                                              const uint32_t* __restrict__ T,
                                              float* __restrict__ part) {
    __shared__ float sout[16][132];
    const int t     = threadIdx.x;
    const int wv    = t >> 6;
    const int lane  = t & 63;
    const int bx    = blockIdx.x;
    const int xcd   = bx & 7;                     // round-robin XCD id
    const int slice = xcd & 3;                    // i-slice pinned to this XCD
    const int jb    = (bx >> 3) * 2 + ((xcd >> 2) & 1);   // b-tile [0,512)
    const int bblk  = jb * 16;
    const int i0    = slice * ISL;
    const int b0    = __builtin_amdgcn_readfirstlane(bblk + wv * 2); // SGPR
    const bool hi   = lane >= 32;
    const uint32_t laneoff = (uint32_t)((lane & 31) * 16);

    const char* Qb = (const char*)Q;
    float a0 = 0.f, a1 = 0.f, a2 = 0.f, a3 = 0.f;
    #pragma unroll 8
    for (int i = i0; i < i0 + ISL; ++i) {
        uint64_t tt = *(const uint64_t*)(T + (size_t)i * NB + b0);
        uint32_t t0 = (uint32_t)tt;
        uint32_t t1 = (uint32_t)(tt >> 32);
        uint32_t w0 = (t0 & 0xFFFF0000u) | 0x3C00u;    // {lo=1.0h, hi=d0}
        uint32_t w1 = (t1 & 0xFFFF0000u) | 0x3C00u;
        uint32_t q0 = (t0 & 127u) << 9;                // idx * 512 B
        uint32_t q1 = (t1 & 127u) << 9;
        uint32_t wb  = hi ? w1 : w0;                   // v_cndmask
        uint32_t off = (uint32_t)(i << 16) + (hi ? q1 : q0) + laneoff;
        uint4 q = *(const uint4*)(Qb + off);           // dwordx4, 2x512B runs
        half2v w2 = __builtin_bit_cast(half2v, wb);
        a0 = __builtin_amdgcn_fdot2(__builtin_bit_cast(half2v, q.x), w2, a0, false);
        a1 = __builtin_amdgcn_fdot2(__builtin_bit_cast(half2v, q.y), w2, a1, false);
        a2 = __builtin_amdgcn_fdot2(__builtin_bit_cast(half2v, q.z), w2, a2, false);
        a3 = __builtin_amdgcn_fdot2(__builtin_bit_cast(half2v, q.w), w2, a3, false);
    }
    {
        int r = wv * 2 + (hi ? 1 : 0);
        int c = (lane & 31) * 4;
        *(float4*)&sout[r][c] = make_float4(a0, a1, a2, a3);
    }
    __syncthreads();
    // partial store: per o, 16 consecutive b; NT to keep pinned Q in L2
    float* ps = part + (size_t)slice * NO * NB;
    {
        int o  = t >> 2;
        int bq = t & 3;
        size_t base = (size_t)o * NB + bblk + bq * 4;
        __builtin_nontemporal_store(sout[bq * 4 + 0][o], &ps[base + 0]);
        __builtin_nontemporal_store(sout[bq * 4 + 1][o], &ps[base + 1]);
        __builtin_nontemporal_store(sout[bq * 4 + 2][o], &ps[base + 2]);
        __builtin_nontemporal_store(sout[bq * 4 + 3][o], &ps[base + 3]);
    }
}

// ---- K4: reduce 4 partial slices -> out ----
__global__ __launch_bounds__(256) void reduce_k(const float* __restrict__ part,
                                                float* __restrict__ out) {
    const size_t f = ((size_t)blockIdx.x * 256 + threadIdx.x) * 4;
    const size_t S = (size_t)NO * NB;
    float4v a = __builtin_nontemporal_load((const float4v*)(part + f));
    float4v b = __builtin_nontemporal_load((const float4v*)(part + f + S));
    float4v c = __builtin_nontemporal_load((const float4v*)(part + f + 2 * S));
    float4v d = __builtin_nontemporal_load((const float4v*)(part + f + 3 * S));
    float4v r = a + b + c + d;
    __builtin_nontemporal_store(r, (float4v*)(out + f));
}

extern "C" void kernel_launch(void* const* d_in, const int* in_sizes, int n_in,
                              void* d_out, int out_size, void* d_ws, size_t ws_size,
                              hipStream_t stream) {
    const float* x       = (const float*)d_in[0];
    const float* P       = (const float*)d_in[1];
    const float* borders = (const float*)d_in[2];
    const float* icl     = (const float*)d_in[3];
    float* out = (float*)d_out;

    uint32_t* Q    = (uint32_t*)d_ws;                   // 8.4 MB
    uint32_t* T    = Q + (size_t)NI * NG * NO;          // 4.2 MB
    float*    part = (float*)(T + (size_t)NI * NB);     // 4*4.2 = 16.8 MB

    hipLaunchKernelGGL(build_q, dim3(NG * 4), dim3(256), 0, stream, P, Q);
    hipLaunchKernelGGL(build_t, dim3(NI * NB / 1024), dim3(256), 0, stream,
                       x, borders, icl, T);
    hipLaunchKernelGGL(main_k, dim3(NB / 16 * NSL), dim3(512), 0, stream,
                       Q, T, part);
    hipLaunchKernelGGL(reduce_k, dim3(NO * NB / 1024), dim3(256), 0, stream,
                       part, out);
}

// Round 6
// 100.990 us; speedup vs baseline: 1.0126x; 1.0126x over previous
//
#include <hip/hip_runtime.h>
#include <cstdint>

// BasisFunction1D: out[o,b] = sum_i (1-d)*P[idx,o,i] + d*P[idx+1,o,i]
//
// R5 strategy (LDS slab-broadcast; gathers on DS pipe, staging on TA pipe):
//   Q2[s][i][g][ow] (s=o/4, ow=o%4): per-(s,i) slab = 128 g x 16 B = 2 KB
//     contiguous -> staged to LDS with full-line global_load_lds_dwordx4.
//   main: block = 1024 thr = 16 waves, owns 1024 b x 4 o (grid 256 = 1/CU).
//     Phases of 8 i, double-buffered 32 KB LDS. Per (lane, i): T load
//     (contiguous), ds_read_b128 at idx*16 (LDS gather, ~8x reuse per row),
//     4 fdot2. Barrier once per phase -> vmcnt(0) drain amortized.

#define NG 128   // grids
#define NI 128   // input dim
#define NO 128   // output dim
#define NB 8192  // batch
#define WO 4     // o per slice
#define PH 8     // i per phase
#define NPH (NI / PH)

using half2v = __attribute__((ext_vector_type(2))) _Float16;

__device__ inline uint32_t pack_f16x2(float lo, float hi) {
    _Float16 hl = (_Float16)lo, hh = (_Float16)hi;
    return (uint32_t)__builtin_bit_cast(unsigned short, hl) |
           ((uint32_t)__builtin_bit_cast(unsigned short, hh) << 16);
}

// ---- K1: P[g,o,i] -> Q2[(s*128+i)*128+g]*4+ow = pack(P, dP), o=s*4+ow ----
__global__ __launch_bounds__(256) void build_q(const float* __restrict__ P,
                                               uint32_t* __restrict__ Q2) {
    __shared__ float lp[32][129];
    __shared__ float ln[32][129];
    const int g  = blockIdx.x >> 2;
    const int o0 = (blockIdx.x & 3) * 32;
    const int t  = threadIdx.x;
    #pragma unroll
    for (int p = 0; p < 16; ++p) {
        int e = p * 256 + t;
        int ol = e >> 7, i = e & 127;
        lp[ol][i] = P[(size_t)(g * NO + o0 + ol) * NI + i];
        ln[ol][i] = P[(size_t)((g + 1) * NO + o0 + ol) * NI + i];
    }
    __syncthreads();
    // one uint4 per (s,i): ow 0..3 packed; dst 16-B aligned contiguous
    #pragma unroll
    for (int p = 0; p < 4; ++p) {
        int e = p * 256 + t;          // e in [0,1024): 8 s_loc x 128 i
        int sl = e >> 7, i = e & 127;
        uint32_t r[4];
        #pragma unroll
        for (int ow = 0; ow < 4; ++ow) {
            float pl = lp[sl * 4 + ow][i];
            float dd = ln[sl * 4 + ow][i] - pl;
            r[ow] = pack_f16x2(pl, dd);
        }
        int s = (o0 >> 2) + sl;
        *(uint4*)(Q2 + ((size_t)(s * NI + i) * NG + g) * 4) =
            make_uint4(r[0], r[1], r[2], r[3]);
    }
}

// ---- K2: bucketize x -> T[i][b] = {u16 idx | f16 d << 16}; x layout ----
__global__ __launch_bounds__(256) void build_t(const float* __restrict__ x,
                                               const float* __restrict__ borders,
                                               const float* __restrict__ icl,
                                               uint32_t* __restrict__ T) {
    const int e0 = (blockIdx.x * 256 + threadIdx.x) * 4;
    const float4 xv = *(const float4*)(x + e0);
    uint32_t r[4];
    const float xs[4] = {xv.x, xv.y, xv.z, xv.w};
    #pragma unroll
    for (int k = 0; k < 4; ++k) {
        float v = xs[k];
        float ea = __expf(-fabsf(v));
        float cdf = v > 0.f ? 1.f - 0.5f * ea : 0.5f * ea;
        int idx = (int)(cdf * 128.f);
        idx = idx > 127 ? 127 : idx;
        float d = (v - borders[idx]) * icl[idx];
        _Float16 hd = (_Float16)d;
        r[k] = (uint32_t)idx |
               ((uint32_t)__builtin_bit_cast(unsigned short, hd) << 16);
    }
    *(uint4*)(T + e0) = make_uint4(r[0], r[1], r[2], r[3]);
}

// ---- K3: main. 1024 thr / 16 waves; 1024 b x 4 o per block; LDS slabs ----
__global__ __launch_bounds__(1024) void main_k(const uint32_t* __restrict__ Q2,
                                               const uint32_t* __restrict__ T,
                                               float* __restrict__ out) {
    __shared__ uint32_t slab[2][PH][NG * WO];   // 2 x 8 x 2 KB = 32 KB
    const int t    = threadIdx.x;
    const int wv   = t >> 6;
    const int lane = t & 63;
    const int bx   = blockIdx.x;
    const int s    = bx & 31;                   // o-slice
    const int bblk = (bx >> 5) << 10;           // b-tile of 1024
    const int bme  = bblk + (wv << 6) + lane;   // lane's batch (fixed)
    const uint32_t* Qs = Q2 + (size_t)s * NI * NG * WO;
    // staging job: wave wv -> slab i_local = wv>>1, half = wv&1 (1024 B)
    const int st_il = wv >> 1;
    const int st_k  = ((wv & 1) << 8) + (lane << 2);   // element offset in slab

    float a0 = 0.f, a1 = 0.f, a2 = 0.f, a3 = 0.f;

    // prologue: stage phase 0 into buf 0
    {
        const uint32_t* src = Qs + (size_t)st_il * (NG * WO) + st_k;
        __builtin_amdgcn_global_load_lds(
            (const __attribute__((address_space(1))) uint32_t*)src,
            (__attribute__((address_space(3))) uint32_t*)&slab[0][st_il][st_k],
            16, 0, 0);
    }
    __syncthreads();

    for (int p = 0; p < NPH; ++p) {
        const int cur = p & 1;
        if (p < NPH - 1) {
            const uint32_t* src =
                Qs + (size_t)((p + 1) * PH + st_il) * (NG * WO) + st_k;
            __builtin_amdgcn_global_load_lds(
                (const __attribute__((address_space(1))) uint32_t*)src,
                (__attribute__((address_space(3))) uint32_t*)
                    &slab[cur ^ 1][st_il][st_k],
                16, 0, 0);
        }
        const uint32_t* Trow = T + (size_t)p * PH * NB + bme;
        #pragma unroll
        for (int il = 0; il < PH; ++il) {
            uint32_t tw  = Trow[(size_t)il * NB];
            uint32_t w2b = (tw & 0xFFFF0000u) | 0x3C00u;   // {1.0h, d}
            uint32_t off = (tw & 127u) << 2;               // idx*4 elements
            uint4 q = *(const uint4*)&slab[cur][il][off];  // ds_read_b128
            half2v w2 = __builtin_bit_cast(half2v, w2b);
            a0 = __builtin_amdgcn_fdot2(__builtin_bit_cast(half2v, q.x), w2, a0, false);
            a1 = __builtin_amdgcn_fdot2(__builtin_bit_cast(half2v, q.y), w2, a1, false);
            a2 = __builtin_amdgcn_fdot2(__builtin_bit_cast(half2v, q.z), w2, a2, false);
            a3 = __builtin_amdgcn_fdot2(__builtin_bit_cast(half2v, q.w), w2, a3, false);
        }
        __syncthreads();
    }

    // epilogue: o = s*4 + {0..3}; 64 lanes = 256 B contiguous per o
    size_t ob = (size_t)(s * 4) * NB + bme;
    __builtin_nontemporal_store(a0, out + ob);
    __builtin_nontemporal_store(a1, out + ob + NB);
    __builtin_nontemporal_store(a2, out + ob + 2 * (size_t)NB);
    __builtin_nontemporal_store(a3, out + ob + 3 * (size_t)NB);
}

extern "C" void kernel_launch(void* const* d_in, const int* in_sizes, int n_in,
                              void* d_out, int out_size, void* d_ws, size_t ws_size,
                              hipStream_t stream) {
    const float* x       = (const float*)d_in[0];
    const float* P       = (const float*)d_in[1];
    const float* borders = (const float*)d_in[2];
    const float* icl     = (const float*)d_in[3];
    float* out = (float*)d_out;

    uint32_t* Q2 = (uint32_t*)d_ws;                 // 32*128*128*4 u32 = 8.4 MB
    uint32_t* T  = Q2 + (size_t)NO * NI * NG;       // 128*8192 u32 = 4.2 MB

    hipLaunchKernelGGL(build_q, dim3(NG * 4), dim3(256), 0, stream, P, Q2);
    hipLaunchKernelGGL(build_t, dim3(NI * NB / 1024), dim3(256), 0, stream,
                       x, borders, icl, T);
    hipLaunchKernelGGL(main_k, dim3((NB / 1024) * 32), dim3(1024), 0, stream,
                       Q2, T, out);
}

// Round 7
// 93.717 us; speedup vs baseline: 1.0912x; 1.0776x over previous
//
#include <hip/hip_runtime.h>
#include <cstdint>

// BasisFunction1D: out[o,b] = sum_i (1-d)*P[idx,o,i] + d*P[idx+1,o,i]
//
// R6 strategy (lean LDS slab path):
//   Q2[s][i][g][ow]: per-(s,i) slab = 128 g x 16 B = 2 KB contiguous.
//   T[i][b] = (idx*16) | (f16(d) << 16)   -- low16 is a ready byte offset.
//   main: 1024 thr = 16 waves = 1024 b x 4 o per block, grid 256 (1/CU).
//     16 fully-unrolled phases of 8 i, double-buffered 32 KB LDS.
//     Staging via regs: dwordx4 load (phase p+1) issued at top of phase p,
//     ds_write_b128 just before the barrier. T prefetched one phase ahead.
//     Inner iter: v_and (ds addr) + v_and_or (weight) + ds_read_b128 + 4 fdot2.

#define NG 128
#define NI 128
#define NO 128
#define NB 8192
#define WO 4
#define PH 8
#define NPH (NI / PH)

using half2v = __attribute__((ext_vector_type(2))) _Float16;

__device__ inline uint32_t pack_f16x2(float lo, float hi) {
    _Float16 hl = (_Float16)lo, hh = (_Float16)hi;
    return (uint32_t)__builtin_bit_cast(unsigned short, hl) |
           ((uint32_t)__builtin_bit_cast(unsigned short, hh) << 16);
}

// ---- K1: P[g,o,i] -> Q2[((s*NI+i)*NG+g)*4+ow] = pack(P, dP), o=s*4+ow ----
__global__ __launch_bounds__(256) void build_q(const float* __restrict__ P,
                                               uint32_t* __restrict__ Q2) {
    __shared__ float lp[32][129];
    __shared__ float ln[32][129];
    const int g  = blockIdx.x >> 2;
    const int o0 = (blockIdx.x & 3) * 32;
    const int t  = threadIdx.x;
    #pragma unroll
    for (int p = 0; p < 16; ++p) {
        int e = p * 256 + t;
        int ol = e >> 7, i = e & 127;
        lp[ol][i] = P[(size_t)(g * NO + o0 + ol) * NI + i];
        ln[ol][i] = P[(size_t)((g + 1) * NO + o0 + ol) * NI + i];
    }
    __syncthreads();
    #pragma unroll
    for (int p = 0; p < 4; ++p) {
        int e = p * 256 + t;          // 8 s_loc x 128 i
        int sl = e >> 7, i = e & 127;
        uint32_t r[4];
        #pragma unroll
        for (int ow = 0; ow < 4; ++ow) {
            float pl = lp[sl * 4 + ow][i];
            float dd = ln[sl * 4 + ow][i] - pl;
            r[ow] = pack_f16x2(pl, dd);
        }
        int s = (o0 >> 2) + sl;
        *(uint4*)(Q2 + ((size_t)(s * NI + i) * NG + g) * 4) =
            make_uint4(r[0], r[1], r[2], r[3]);
    }
}

// ---- K2: bucketize x -> T[i][b] = (idx*16) | (f16(d) << 16) ----
__global__ __launch_bounds__(256) void build_t(const float* __restrict__ x,
                                               const float* __restrict__ borders,
                                               const float* __restrict__ icl,
                                               uint32_t* __restrict__ T) {
    const int e0 = (blockIdx.x * 256 + threadIdx.x) * 4;
    const float4 xv = *(const float4*)(x + e0);
    uint32_t r[4];
    const float xs[4] = {xv.x, xv.y, xv.z, xv.w};
    #pragma unroll
    for (int k = 0; k < 4; ++k) {
        float v = xs[k];
        float ea = __expf(-fabsf(v));
        float cdf = v > 0.f ? 1.f - 0.5f * ea : 0.5f * ea;
        int idx = (int)(cdf * 128.f);
        idx = idx > 127 ? 127 : idx;
        float d = (v - borders[idx]) * icl[idx];
        _Float16 hd = (_Float16)d;
        r[k] = ((uint32_t)idx << 4) |
               ((uint32_t)__builtin_bit_cast(unsigned short, hd) << 16);
    }
    *(uint4*)(T + e0) = make_uint4(r[0], r[1], r[2], r[3]);
}

// ---- K3: main. 1024 thr; 1024 b x 4 o; reg-staged double-buffered slabs ----
__global__ __launch_bounds__(1024) void main_k(const uint32_t* __restrict__ Q2,
                                               const uint32_t* __restrict__ T,
                                               float* __restrict__ out) {
    __shared__ uint32_t slab[2][PH][NG * WO];   // 32 KB
    const int t    = threadIdx.x;
    const int bx   = blockIdx.x;
    const int s    = bx & 31;                   // o-slice (4 o)
    const int bblk = (bx >> 5) << 10;           // b-tile of 1024
    const int bme  = bblk + t;                  // lane's batch
    const uint32_t* Qs = Q2 + (size_t)s * NI * NG * WO;

    float a0 = 0.f, a1 = 0.f, a2 = 0.f, a3 = 0.f;

    // prologue: stage phase 0
    uint32_t treg[PH];
    {
        uint4 q0 = *(const uint4*)(Qs + (size_t)t * 4);
        #pragma unroll
        for (int il = 0; il < PH; ++il)
            treg[il] = T[(size_t)il * NB + bme];
        ((uint4*)&slab[0][0][0])[t] = q0;
    }
    __syncthreads();

    #pragma unroll
    for (int p = 0; p < NPH; ++p) {
        const int cur = p & 1;
        uint32_t tnxt[PH];
        uint4 qnxt;
        if (p < NPH - 1) {
            qnxt = *(const uint4*)(Qs + (size_t)(p + 1) * (PH * NG * WO) +
                                   (size_t)t * 4);
            #pragma unroll
            for (int il = 0; il < PH; ++il)
                tnxt[il] = T[(size_t)((p + 1) * PH + il) * NB + bme];
        }
        #pragma unroll
        for (int il = 0; il < PH; ++il) {
            uint32_t tw  = treg[il];
            uint32_t off = tw & 0xFFFFu;                    // idx*16 bytes
            uint32_t w2b = (tw & 0xFFFF0000u) | 0x3C00u;    // {1.0h, d}
            uint4 q = *(const uint4*)((const char*)&slab[cur][il][0] + off);
            half2v w2 = __builtin_bit_cast(half2v, w2b);
            a0 = __builtin_amdgcn_fdot2(__builtin_bit_cast(half2v, q.x), w2, a0, false);
            a1 = __builtin_amdgcn_fdot2(__builtin_bit_cast(half2v, q.y), w2, a1, false);
            a2 = __builtin_amdgcn_fdot2(__builtin_bit_cast(half2v, q.z), w2, a2, false);
            a3 = __builtin_amdgcn_fdot2(__builtin_bit_cast(half2v, q.w), w2, a3, false);
        }
        if (p < NPH - 1) {
            ((uint4*)&slab[cur ^ 1][0][0])[t] = qnxt;
            #pragma unroll
            for (int il = 0; il < PH; ++il)
                treg[il] = tnxt[il];
            __syncthreads();
        }
    }

    // epilogue: o = s*4 + {0..3}; 64-lane contiguous runs per o
    size_t ob = (size_t)(s * 4) * NB + bme;
    __builtin_nontemporal_store(a0, out + ob);
    __builtin_nontemporal_store(a1, out + ob + NB);
    __builtin_nontemporal_store(a2, out + ob + 2 * (size_t)NB);
    __builtin_nontemporal_store(a3, out + ob + 3 * (size_t)NB);
}

extern "C" void kernel_launch(void* const* d_in, const int* in_sizes, int n_in,
                              void* d_out, int out_size, void* d_ws, size_t ws_size,
                              hipStream_t stream) {
    const float* x       = (const float*)d_in[0];
    const float* P       = (const float*)d_in[1];
    const float* borders = (const float*)d_in[2];
    const float* icl     = (const float*)d_in[3];
    float* out = (float*)d_out;

    uint32_t* Q2 = (uint32_t*)d_ws;                 // 8.4 MB
    uint32_t* T  = Q2 + (size_t)NO * NI * NG;       // 4.2 MB

    hipLaunchKernelGGL(build_q, dim3(NG * 4), dim3(256), 0, stream, P, Q2);
    hipLaunchKernelGGL(build_t, dim3(NI * NB / 1024), dim3(256), 0, stream,
                       x, borders, icl, T);
    hipLaunchKernelGGL(main_k, dim3((NB / 1024) * 32), dim3(1024), 0, stream,
                       Q2, T, out);
}